// Round 1
// baseline (2126.580 us; speedup 1.0000x reference)
//
#include <hip/hip_runtime.h>
#include <math.h>

// Problem constants
constexpr int DD    = 512;     // D
constexpr int D2    = 1024;    // 2D
constexpr int NTOK  = 256;     // vocab V (unique tokens = unique pipelines)
constexpr int NSYM  = 512;
constexpr int NCON  = 64;
constexpr int VOCAB = 256;
constexpr int BS_TOT = 32 * 512;   // B*S = 16384
constexpr int NDEPTH = 6;
constexpr int NLOOK  = 3;
constexpr float EPSF = 1e-8f;
constexpr float SCALE = 0.044194173824159216f; // 512^-0.5

// ---------------- init / histogram ----------------
__global__ void zero_kernel(float* symErr, float* conErr, int* hist) {
    int t = threadIdx.x;
    symErr[t] = 0.f; conErr[t] = 0.f; hist[t] = 0;
}

__global__ void hist_kernel(const int* __restrict__ x, int* __restrict__ hist) {
    int i = blockIdx.x * 256 + threadIdx.x;
    atomicAdd(&hist[x[i]], 1);
}

// ---------------- embedding: z = (mag*cos(phase), mag*sin(phase)) ----------------
__global__ void embed_kernel(const float* __restrict__ mag, const float* __restrict__ phase,
                             float* __restrict__ dst) {
    int v = blockIdx.x, j = threadIdx.x;          // block 512
    float r = mag[v * DD + j], t = phase[v * DD + j];
    dst[v * D2 + j]      = r * cosf(t);
    dst[v * D2 + DD + j] = r * sinf(t);
}

// ---------------- sym code norms ----------------
__global__ void symnorm_kernel(const float* __restrict__ sym, float* __restrict__ snorm) {
    int c = blockIdx.x, tid = threadIdx.x;        // block 256, 256 float4s per row
    const float4* r = (const float4*)(sym + (size_t)c * D2);
    float4 v = r[tid];
    float p = v.x*v.x + v.y*v.y + v.z*v.z + v.w*v.w;
    __shared__ float red[256];
    red[tid] = p; __syncthreads();
    for (int off = 128; off > 0; off >>= 1) {
        if (tid < off) red[tid] += red[tid + off];
        __syncthreads();
    }
    if (tid == 0) snorm[c] = red[0];
}

// ---------------- cell: complex matvec + saturating norm + tanh ----------------
// grid (2, 64): x = j-chunk of 256, y = group of 4 tokens. block 256.
__global__ __launch_bounds__(256) void cell_kernel(const float* __restrict__ src,
                                                   float* __restrict__ dst,
                                                   const float* __restrict__ Wr,
                                                   const float* __restrict__ Wi) {
    __shared__ __align__(16) float s[4 * D2];
    int t0 = blockIdx.y * 4;
    const float4* g = (const float4*)(src + (size_t)t0 * D2);
    float4* s4w = (float4*)s;
    for (int i = threadIdx.x; i < 4 * D2 / 4; i += 256) s4w[i] = g[i];
    __syncthreads();

    int j = blockIdx.x * 256 + threadIdx.x;
    const float4* wr4 = (const float4*)(Wr + (size_t)j * DD);
    const float4* wi4 = (const float4*)(Wi + (size_t)j * DD);
    const float4* s4 = (const float4*)s;
    float ar[4] = {0,0,0,0}, ai[4] = {0,0,0,0};
    for (int k4 = 0; k4 < DD / 4; ++k4) {
        float4 wr = wr4[k4], wi = wi4[k4];
#pragma unroll
        for (int t = 0; t < 4; ++t) {
            float4 zr = s4[t * (D2/4) + k4];
            float4 zi = s4[t * (D2/4) + (DD/4) + k4];
            ar[t] += wr.x*zr.x + wr.y*zr.y + wr.z*zr.z + wr.w*zr.w;
            ar[t] -= wi.x*zi.x + wi.y*zi.y + wi.z*zi.z + wi.w*zi.w;
            ai[t] += wr.x*zi.x + wr.y*zi.y + wr.z*zi.z + wr.w*zi.w;
            ai[t] += wi.x*zr.x + wi.y*zr.y + wi.z*zr.z + wi.w*zr.w;
        }
    }
#pragma unroll
    for (int t = 0; t < 4; ++t) {
        float m = sqrtf(ar[t]*ar[t] + ai[t]*ai[t] + EPSF);
        float inv = 1.0f / (1.0f + m);
        dst[(size_t)(t0 + t) * D2 + j]      = tanhf(ar[t] * inv);
        dst[(size_t)(t0 + t) * D2 + DD + j] = tanhf(ai[t] * inv);
    }
}

// ---------------- generic batched matvec: dst[t][j] = W[j,:]·src[t,:] + b[j] ----------------
// grid (out_dim/256, 64), block 256, 4 tokens per block.
__global__ __launch_bounds__(256) void matvec_kernel(const float* __restrict__ W,
                                                     const float* __restrict__ bias,
                                                     const float* __restrict__ src,
                                                     float* __restrict__ dst,
                                                     int in_dim, int out_dim) {
    __shared__ __align__(16) float s[4 * D2];
    int t0 = blockIdx.y * 4;
    const float4* g = (const float4*)(src + (size_t)t0 * in_dim);
    float4* s4w = (float4*)s;
    int n4 = 4 * in_dim / 4;
    for (int i = threadIdx.x; i < n4; i += 256) s4w[i] = g[i];
    __syncthreads();

    int j = blockIdx.x * 256 + threadIdx.x;
    const float4* w4 = (const float4*)(W + (size_t)j * in_dim);
    const float4* s4 = (const float4*)s;
    int K4 = in_dim / 4;
    float acc[4] = {0,0,0,0};
    for (int k4 = 0; k4 < K4; ++k4) {
        float4 w = w4[k4];
#pragma unroll
        for (int t = 0; t < 4; ++t) {
            float4 xv = s4[t * K4 + k4];
            acc[t] += w.x*xv.x + w.y*xv.y + w.z*xv.z + w.w*xv.w;
        }
    }
    float b = bias[j];
#pragma unroll
    for (int t = 0; t < 4; ++t)
        dst[(size_t)(t0 + t) * out_dim + j] = acc[t] + b;
}

// ---------------- attend (light part): scores, softmax, ctx update ----------------
// grid 256 (token), block 256. Q precomputed. M = number of memory entries.
__global__ __launch_bounds__(256) void attend_kernel(float* __restrict__ z,
                                                     const float* __restrict__ Q,
                                                     const float* __restrict__ Kmem,
                                                     const float* __restrict__ Vmem,
                                                     const float* __restrict__ conf,
                                                     int M) {
    int v = blockIdx.x, tid = threadIdx.x;
    __shared__ float red[256];
    __shared__ float s_sc[8];
    float q0 = Q[(size_t)v * DD + tid];
    float q1 = Q[(size_t)v * DD + 256 + tid];
    for (int m = 0; m < M; ++m) {
        const float* K = Kmem + (size_t)m * NTOK * DD + (size_t)v * DD;
        red[tid] = q0 * K[tid] + q1 * K[256 + tid];
        __syncthreads();
        for (int off = 128; off > 0; off >>= 1) {
            if (tid < off) red[tid] += red[tid + off];
            __syncthreads();
        }
        if (tid == 0) s_sc[m] = red[0] * SCALE * conf[v];
        __syncthreads();
    }
    if (tid == 0) {
        float mx = s_sc[0];
        for (int m = 1; m < M; ++m) mx = fmaxf(mx, s_sc[m]);
        float w[5], sum = 0.f;
        for (int m = 0; m < M; ++m) { w[m] = expf(s_sc[m] - mx); sum += w[m]; }
        for (int m = 0; m < M; ++m) s_sc[m] = w[m] / sum;
    }
    __syncthreads();
#pragma unroll
    for (int r = 0; r < 4; ++r) {
        int e = r * 256 + tid;
        float ctx = 0.f;
        for (int m = 0; m < M; ++m)
            ctx += s_sc[m] * Vmem[(size_t)m * NTOK * D2 + (size_t)v * D2 + e];
        z[(size_t)v * D2 + e] += 0.1f * ctx;
    }
}

// ---------------- quantize (sym + con) ----------------
// grid 128 (2 tokens/block), block 512 (one sym code per thread).
__global__ __launch_bounds__(512) void quantize_kernel(float* __restrict__ z,
                                                       const float* __restrict__ sym,
                                                       const float* __restrict__ snorm,
                                                       const float* __restrict__ con,
                                                       float* __restrict__ conf,
                                                       float* __restrict__ symErr,
                                                       float* __restrict__ conErr) {
    int t0 = blockIdx.x * 2;
    int tid = threadIdx.x;
    __shared__ __align__(16) float s_z[2 * D2];
    __shared__ float s_red[512];
    __shared__ int   s_idx[512];
    __shared__ float s_res[8];   // [znorm0, znorm1, sd0, sd1, zsnorm0, zsnorm1]
    __shared__ int   s_si[2];

    {   // stage both tokens' z
        const float4* g = (const float4*)(z + (size_t)t0 * D2);
        float4* s4w = (float4*)s_z;
        if (tid < 512) { s4w[tid] = g[tid]; }   // 512 float4 = 2048 floats
    }
    __syncthreads();

    // ||z||^2 per token (pre-update, matches reference d for conf)
    for (int t = 0; t < 2; ++t) {
        float a = s_z[t * D2 + tid], b = s_z[t * D2 + 512 + tid];
        s_red[tid] = a * a + b * b;
        __syncthreads();
        for (int off = 256; off > 0; off >>= 1) {
            if (tid < off) s_red[tid] += s_red[tid + off];
            __syncthreads();
        }
        if (tid == 0) s_res[t] = s_red[0];
        __syncthreads();
    }

    // distances to all 512 sym codes (thread = code)
    const float4* cr = (const float4*)(sym + (size_t)tid * D2);
    const float4* z4 = (const float4*)s_z;
    float dot0 = 0.f, dot1 = 0.f;
    for (int k4 = 0; k4 < D2 / 4; ++k4) {
        float4 c4 = cr[k4];
        float4 a = z4[k4];
        float4 b = z4[D2/4 + k4];
        dot0 += c4.x*a.x + c4.y*a.y + c4.z*a.z + c4.w*a.w;
        dot1 += c4.x*b.x + c4.y*b.y + c4.z*b.z + c4.w*b.w;
    }
    float cn = snorm[tid];
    float d0 = s_res[0] + cn - 2.f * dot0;
    float d1 = s_res[1] + cn - 2.f * dot1;

    // argmin per token (first-min tie-break like jnp.argmin)
    for (int t = 0; t < 2; ++t) {
        s_red[tid] = t ? d1 : d0;
        s_idx[tid] = tid;
        __syncthreads();
        for (int off = 256; off > 0; off >>= 1) {
            if (tid < off) {
                float o = s_red[tid + off]; int oi = s_idx[tid + off];
                if (o < s_red[tid] || (o == s_red[tid] && oi < s_idx[tid])) {
                    s_red[tid] = o; s_idx[tid] = oi;
                }
            }
            __syncthreads();
        }
        if (tid == 0) { s_res[2 + t] = s_red[0]; s_si[t] = s_idx[0]; }
        __syncthreads();
    }

    // conf, straight-through state update, symErr (direct form)
    for (int t = 0; t < 2; ++t) {
        int si = s_si[t];
        if (tid == 0) conf[t0 + t] = 1.0f / (1.0f + s_res[2 + t]);
        const float* crow = sym + (size_t)si * D2;
        float errp = 0.f;
#pragma unroll
        for (int r = 0; r < 2; ++r) {
            int e = r * 512 + tid;
            float zf = s_z[t * D2 + e];
            float diff = crow[e] - zf;
            errp += diff * diff;
            float zn = zf + diff;      // zs = z + (c - z), exact straight-through fp
            s_z[t * D2 + e] = zn;
            z[(size_t)(t0 + t) * D2 + e] = zn;
        }
        s_red[tid] = errp;
        __syncthreads();
        for (int off = 256; off > 0; off >>= 1) {
            if (tid < off) s_red[tid] += s_red[tid + off];
            __syncthreads();
        }
        if (tid == 0) symErr[t0 + t] += s_red[0];
        __syncthreads();
    }

    // ||zs||^2 per token (for con expanded distance)
    for (int t = 0; t < 2; ++t) {
        float a = s_z[t * D2 + tid], b = s_z[t * D2 + 512 + tid];
        s_red[tid] = a * a + b * b;
        __syncthreads();
        for (int off = 256; off > 0; off >>= 1) {
            if (tid < off) s_red[tid] += s_red[tid + off];
            __syncthreads();
        }
        if (tid == 0) s_res[4 + t] = s_red[0];
        __syncthreads();
    }

    // con quantize: 2 tokens x 64 codes on threads 0..127
    if (tid < 128) {
        int t = tid >> 6, c = tid & 63;
        const float4* crow = (const float4*)(con + (size_t)c * D2);
        const float4* zz = (const float4*)(s_z + (size_t)t * D2);
        float dot = 0.f, cn2 = 0.f;
        for (int k4 = 0; k4 < D2 / 4; ++k4) {
            float4 cc = crow[k4], a = zz[k4];
            dot += cc.x*a.x + cc.y*a.y + cc.z*a.z + cc.w*a.w;
            cn2 += cc.x*cc.x + cc.y*cc.y + cc.z*cc.z + cc.w*cc.w;
        }
        s_red[tid] = s_res[4 + t] + cn2 - 2.f * dot;
        s_idx[tid] = c;
    }
    __syncthreads();
    for (int off = 32; off > 0; off >>= 1) {
        if (tid < 128 && (tid & 63) < off) {
            float o = s_red[tid + off]; int oi = s_idx[tid + off];
            if (o < s_red[tid] || (o == s_red[tid] && oi < s_idx[tid])) {
                s_red[tid] = o; s_idx[tid] = oi;
            }
        }
        __syncthreads();
    }
    int ci0 = s_idx[0], ci1 = s_idx[64];
    __syncthreads();

    // conErr (direct form, vs actual zs)
    for (int t = 0; t < 2; ++t) {
        int ci = t ? ci1 : ci0;
        const float* crow = con + (size_t)ci * D2;
        float p = 0.f;
#pragma unroll
        for (int r = 0; r < 2; ++r) {
            int e = r * 512 + tid;
            float diff = crow[e] - s_z[t * D2 + e];
            p += diff * diff;
        }
        s_red[tid] = p;
        __syncthreads();
        for (int off = 256; off > 0; off >>= 1) {
            if (tid < off) s_red[tid] += s_red[tid + off];
            __syncthreads();
        }
        if (tid == 0) conErr[t0 + t] += s_red[0];
        __syncthreads();
    }
}

// ---------------- scatter: out[pos] = rows[x[pos]] ----------------
// grid 4096, block 256 (4 positions/block, 64 lanes x float4 each)
__global__ __launch_bounds__(256) void scatter_kernel(const int* __restrict__ x,
                                                      const float* __restrict__ rows,
                                                      float* __restrict__ out) {
    int tid = threadIdx.x;
    int pos = blockIdx.x * 4 + (tid >> 6);
    int lane = tid & 63;
    int v = x[pos];
    const float4* r = (const float4*)(rows + (size_t)v * VOCAB);
    ((float4*)(out + (size_t)pos * VOCAB))[lane] = r[lane];
}

// ---------------- losses ----------------
__global__ void loss_kernel(const int* __restrict__ hist,
                            const float* __restrict__ symErr,
                            const float* __restrict__ conErr,
                            float* __restrict__ out) {
    int tid = threadIdx.x;   // 256
    __shared__ double rs[256], rc[256];
    rs[tid] = (double)hist[tid] * (double)symErr[tid];
    rc[tid] = (double)hist[tid] * (double)conErr[tid];
    __syncthreads();
    for (int off = 128; off > 0; off >>= 1) {
        if (tid < off) { rs[tid] += rs[tid + off]; rc[tid] += rc[tid + off]; }
        __syncthreads();
    }
    if (tid == 0) {
        const double denom = (double)BS_TOT * (double)D2;   // 16777216
        out[(size_t)BS_TOT * VOCAB]     = (float)(1.25 * rs[0] / denom);
        out[(size_t)BS_TOT * VOCAB + 1] = (float)(1.25 * rc[0] / denom);
    }
}

// ---------------- host ----------------
extern "C" void kernel_launch(void* const* d_in, const int* in_sizes, int n_in,
                              void* d_out, int out_size, void* d_ws, size_t ws_size,
                              hipStream_t stream) {
    const int*   x     = (const int*)  d_in[0];
    const float* mag   = (const float*)d_in[1];
    const float* phase = (const float*)d_in[2];
    const float* Wr    = (const float*)d_in[3];
    const float* Wi    = (const float*)d_in[4];
    const float* qw    = (const float*)d_in[5];
    const float* qb    = (const float*)d_in[6];
    const float* kw    = (const float*)d_in[7];
    const float* kb    = (const float*)d_in[8];
    const float* vw    = (const float*)d_in[9];
    const float* vb    = (const float*)d_in[10];
    const float* dec_w = (const float*)d_in[11];
    const float* dec_b = (const float*)d_in[12];
    const float* sym   = (const float*)d_in[13];
    const float* con   = (const float*)d_in[14];
    float* out = (float*)d_out;

    // workspace layout (floats); total ~12.3 MB
    float* ws     = (float*)d_ws;
    float* bufA   = ws;                          // 256*1024
    float* bufB   = bufA + NTOK * D2;            // 256*1024
    float* Qbuf   = bufB + NTOK * D2;            // 256*512
    float* Kmem   = Qbuf + NTOK * DD;            // 6*256*512
    float* Vmem   = Kmem + NDEPTH * NTOK * DD;   // 6*256*1024
    float* rows   = Vmem + NDEPTH * NTOK * D2;   // 256*256
    float* snorm  = rows + NTOK * VOCAB;         // 512
    float* conf   = snorm + NSYM;                // 256
    float* symErr = conf + NTOK;                 // 256
    float* conErr = symErr + NTOK;               // 256
    int*   hist   = (int*)(conErr + NTOK);       // 256

    zero_kernel<<<1, 256, 0, stream>>>(symErr, conErr, hist);
    hist_kernel<<<BS_TOT / 256, 256, 0, stream>>>(x, hist);
    symnorm_kernel<<<NSYM, 256, 0, stream>>>(sym, snorm);
    embed_kernel<<<NTOK, 512, 0, stream>>>(mag, phase, bufA);

    float* cur = bufA;
    float* oth = bufB;
    for (int d = 0; d < NDEPTH; ++d) {
        cell_kernel<<<dim3(2, 64), 256, 0, stream>>>(cur, oth, Wr, Wi);
        { float* t = cur; cur = oth; oth = t; }
        if (d > 0) {
            matvec_kernel<<<dim3(2, 64), 256, 0, stream>>>(qw, qb, cur, Qbuf, D2, DD);
            attend_kernel<<<NTOK, 256, 0, stream>>>(cur, Qbuf, Kmem, Vmem, conf, d);
        }
        quantize_kernel<<<NTOK / 2, 512, 0, stream>>>(cur, sym, snorm, con, conf, symErr, conErr);
        matvec_kernel<<<dim3(2, 64), 256, 0, stream>>>(kw, kb, cur,
                                                       Kmem + (size_t)d * NTOK * DD, D2, DD);
        matvec_kernel<<<dim3(4, 64), 256, 0, stream>>>(vw, vb, cur,
                                                       Vmem + (size_t)d * NTOK * D2, D2, D2);
    }
    for (int l = 0; l < NLOOK; ++l) {
        cell_kernel<<<dim3(2, 64), 256, 0, stream>>>(cur, oth, Wr, Wi);
        { float* t = cur; cur = oth; oth = t; }
    }
    matvec_kernel<<<dim3(1, 64), 256, 0, stream>>>(dec_w, dec_b, cur, rows, D2, VOCAB);
    scatter_kernel<<<BS_TOT / 4, 256, 0, stream>>>(x, rows, out);
    loss_kernel<<<1, 256, 0, stream>>>(hist, symErr, conErr, out);
}

// Round 2
// 1665.212 us; speedup vs baseline: 1.2771x; 1.2771x over previous
//
#include <hip/hip_runtime.h>
#include <math.h>

// Problem constants
constexpr int DD    = 512;     // D
constexpr int D2    = 1024;    // 2D
constexpr int NTOK  = 256;     // vocab V (unique tokens = unique pipelines)
constexpr int NSYM  = 512;
constexpr int NCON  = 64;
constexpr int VOCAB = 256;
constexpr int BS_TOT = 32 * 512;   // B*S = 16384
constexpr int NDEPTH = 6;
constexpr int NLOOK  = 3;
constexpr float EPSF = 1e-8f;
constexpr float SCALE = 0.044194173824159216f; // 512^-0.5

// ---------------- init / histogram ----------------
__global__ void zero_kernel(float* symErr, float* conErr, int* hist) {
    int t = threadIdx.x;
    symErr[t] = 0.f; conErr[t] = 0.f; hist[t] = 0;
}

__global__ void hist_kernel(const int* __restrict__ x, int* __restrict__ hist) {
    int i = blockIdx.x * 256 + threadIdx.x;
    atomicAdd(&hist[x[i]], 1);
}

// ---------------- embedding: z = (mag*cos(phase), mag*sin(phase)) ----------------
__global__ void embed_kernel(const float* __restrict__ mag, const float* __restrict__ phase,
                             float* __restrict__ dst) {
    int v = blockIdx.x, j = threadIdx.x;          // block 512
    float r = mag[v * DD + j], t = phase[v * DD + j];
    dst[v * D2 + j]      = r * cosf(t);
    dst[v * D2 + DD + j] = r * sinf(t);
}

// ---------------- sym code norms ----------------
__global__ void symnorm_kernel(const float* __restrict__ sym, float* __restrict__ snorm) {
    int c = blockIdx.x, tid = threadIdx.x;        // block 256, 256 float4s per row
    const float4* r = (const float4*)(sym + (size_t)c * D2);
    float4 v = r[tid];
    float p = v.x*v.x + v.y*v.y + v.z*v.z + v.w*v.w;
    __shared__ float red[256];
    red[tid] = p; __syncthreads();
    for (int off = 128; off > 0; off >>= 1) {
        if (tid < off) red[tid] += red[tid + off];
        __syncthreads();
    }
    if (tid == 0) snorm[c] = red[0];
}

// ---------------- cell: complex matvec + saturating norm + tanh ----------------
// grid (2, 128): x = j-chunk of 256, y = token pair. block 256.
// Per-output fp expression identical to round-1 version (only decomposition changed).
__global__ __launch_bounds__(256) void cell_kernel(const float* __restrict__ src,
                                                   float* __restrict__ dst,
                                                   const float* __restrict__ Wr,
                                                   const float* __restrict__ Wi) {
    __shared__ __align__(16) float s[2 * D2];
    int t0 = blockIdx.y * 2;
    const float4* g = (const float4*)(src + (size_t)t0 * D2);
    float4* s4w = (float4*)s;
    for (int i = threadIdx.x; i < 2 * D2 / 4; i += 256) s4w[i] = g[i];
    __syncthreads();

    int j = blockIdx.x * 256 + threadIdx.x;
    const float4* wr4 = (const float4*)(Wr + (size_t)j * DD);
    const float4* wi4 = (const float4*)(Wi + (size_t)j * DD);
    const float4* s4 = (const float4*)s;
    float ar[2] = {0,0}, ai[2] = {0,0};
#pragma unroll 4
    for (int k4 = 0; k4 < DD / 4; ++k4) {
        float4 wr = wr4[k4], wi = wi4[k4];
#pragma unroll
        for (int t = 0; t < 2; ++t) {
            float4 zr = s4[t * (D2/4) + k4];
            float4 zi = s4[t * (D2/4) + (DD/4) + k4];
            ar[t] += wr.x*zr.x + wr.y*zr.y + wr.z*zr.z + wr.w*zr.w;
            ar[t] -= wi.x*zi.x + wi.y*zi.y + wi.z*zi.z + wi.w*zi.w;
            ai[t] += wr.x*zi.x + wr.y*zi.y + wr.z*zi.z + wr.w*zi.w;
            ai[t] += wi.x*zr.x + wi.y*zr.y + wi.z*zr.z + wi.w*zr.w;
        }
    }
#pragma unroll
    for (int t = 0; t < 2; ++t) {
        float m = sqrtf(ar[t]*ar[t] + ai[t]*ai[t] + EPSF);
        float inv = 1.0f / (1.0f + m);
        dst[(size_t)(t0 + t) * D2 + j]      = tanhf(ar[t] * inv);
        dst[(size_t)(t0 + t) * D2 + DD + j] = tanhf(ai[t] * inv);
    }
}

// ---------------- generic batched matvec: dst[t][j] = W[j,:]·src[t,:] + b[j] ----------------
// grid (out_dim/256, NTOK/T), block 256, T tokens per block.
// Per-output fp expression identical to round-1 version.
template<int T>
__global__ __launch_bounds__(256) void matvec_kernel(const float* __restrict__ W,
                                                     const float* __restrict__ bias,
                                                     const float* __restrict__ src,
                                                     float* __restrict__ dst,
                                                     int in_dim, int out_dim) {
    __shared__ __align__(16) float s[T * D2];
    int t0 = blockIdx.y * T;
    const float4* g = (const float4*)(src + (size_t)t0 * in_dim);
    float4* s4w = (float4*)s;
    int n4 = T * in_dim / 4;
    for (int i = threadIdx.x; i < n4; i += 256) s4w[i] = g[i];
    __syncthreads();

    int j = blockIdx.x * 256 + threadIdx.x;
    const float4* w4 = (const float4*)(W + (size_t)j * in_dim);
    const float4* s4 = (const float4*)s;
    int K4 = in_dim / 4;
    float acc[T];
#pragma unroll
    for (int t = 0; t < T; ++t) acc[t] = 0.f;
#pragma unroll 4
    for (int k4 = 0; k4 < K4; ++k4) {
        float4 w = w4[k4];
#pragma unroll
        for (int t = 0; t < T; ++t) {
            float4 xv = s4[t * K4 + k4];
            acc[t] += w.x*xv.x + w.y*xv.y + w.z*xv.z + w.w*xv.w;
        }
    }
    float b = bias[j];
#pragma unroll
    for (int t = 0; t < T; ++t)
        dst[(size_t)(t0 + t) * out_dim + j] = acc[t] + b;
}

// ---------------- attend (light part): scores, softmax, ctx update ----------------
// grid 256 (token), block 256. Q precomputed. M = number of memory entries.
__global__ __launch_bounds__(256) void attend_kernel(float* __restrict__ z,
                                                     const float* __restrict__ Q,
                                                     const float* __restrict__ Kmem,
                                                     const float* __restrict__ Vmem,
                                                     const float* __restrict__ conf,
                                                     int M) {
    int v = blockIdx.x, tid = threadIdx.x;
    __shared__ float red[256];
    __shared__ float s_sc[8];
    float q0 = Q[(size_t)v * DD + tid];
    float q1 = Q[(size_t)v * DD + 256 + tid];
    for (int m = 0; m < M; ++m) {
        const float* K = Kmem + (size_t)m * NTOK * DD + (size_t)v * DD;
        red[tid] = q0 * K[tid] + q1 * K[256 + tid];
        __syncthreads();
        for (int off = 128; off > 0; off >>= 1) {
            if (tid < off) red[tid] += red[tid + off];
            __syncthreads();
        }
        if (tid == 0) s_sc[m] = red[0] * SCALE * conf[v];
        __syncthreads();
    }
    if (tid == 0) {
        float mx = s_sc[0];
        for (int m = 1; m < M; ++m) mx = fmaxf(mx, s_sc[m]);
        float w[5], sum = 0.f;
        for (int m = 0; m < M; ++m) { w[m] = expf(s_sc[m] - mx); sum += w[m]; }
        for (int m = 0; m < M; ++m) s_sc[m] = w[m] / sum;
    }
    __syncthreads();
#pragma unroll
    for (int r = 0; r < 4; ++r) {
        int e = r * 256 + tid;
        float ctx = 0.f;
        for (int m = 0; m < M; ++m)
            ctx += s_sc[m] * Vmem[(size_t)m * NTOK * D2 + (size_t)v * D2 + e];
        z[(size_t)v * D2 + e] += 0.1f * ctx;
    }
}

// ---------------- quantize (sym + con) ----------------
// grid 256 (1 token/block), block 512 (one sym code per thread).
// Per-token arithmetic and reduction orders identical to round-1 (which matched bitwise);
// only tokens-per-block changed 2 -> 1 for occupancy.
__global__ __launch_bounds__(512) void quantize_kernel(float* __restrict__ z,
                                                       const float* __restrict__ sym,
                                                       const float* __restrict__ snorm,
                                                       const float* __restrict__ con,
                                                       float* __restrict__ conf,
                                                       float* __restrict__ symErr,
                                                       float* __restrict__ conErr) {
    int t0 = blockIdx.x;
    int tid = threadIdx.x;
    __shared__ __align__(16) float s_z[D2];
    __shared__ float s_red[512];
    __shared__ int   s_idx[512];
    __shared__ float s_res[4];   // [znorm, sd, zsnorm]
    __shared__ int   s_si[1];

    {   // stage token's z: 256 float4 = 1024 floats
        const float4* g = (const float4*)(z + (size_t)t0 * D2);
        float4* s4w = (float4*)s_z;
        if (tid < 256) s4w[tid] = g[tid];
    }
    __syncthreads();

    // ||z||^2 (pre-update, matches reference d for conf)
    {
        float a = s_z[tid], b = s_z[512 + tid];
        s_red[tid] = a * a + b * b;
        __syncthreads();
        for (int off = 256; off > 0; off >>= 1) {
            if (tid < off) s_red[tid] += s_red[tid + off];
            __syncthreads();
        }
        if (tid == 0) s_res[0] = s_red[0];
        __syncthreads();
    }

    // distances to all 512 sym codes (thread = code)
    const float4* cr = (const float4*)(sym + (size_t)tid * D2);
    const float4* z4 = (const float4*)s_z;
    float dot0 = 0.f;
#pragma unroll 4
    for (int k4 = 0; k4 < D2 / 4; ++k4) {
        float4 c4 = cr[k4];
        float4 a = z4[k4];
        dot0 += c4.x*a.x + c4.y*a.y + c4.z*a.z + c4.w*a.w;
    }
    float cn = snorm[tid];
    float d0 = s_res[0] + cn - 2.f * dot0;

    // argmin (first-min tie-break like jnp.argmin)
    {
        s_red[tid] = d0;
        s_idx[tid] = tid;
        __syncthreads();
        for (int off = 256; off > 0; off >>= 1) {
            if (tid < off) {
                float o = s_red[tid + off]; int oi = s_idx[tid + off];
                if (o < s_red[tid] || (o == s_red[tid] && oi < s_idx[tid])) {
                    s_red[tid] = o; s_idx[tid] = oi;
                }
            }
            __syncthreads();
        }
        if (tid == 0) { s_res[1] = s_red[0]; s_si[0] = s_idx[0]; }
        __syncthreads();
    }

    // conf, straight-through state update, symErr (direct form)
    {
        int si = s_si[0];
        if (tid == 0) conf[t0] = 1.0f / (1.0f + s_res[1]);
        const float* crow = sym + (size_t)si * D2;
        float errp = 0.f;
#pragma unroll
        for (int r = 0; r < 2; ++r) {
            int e = r * 512 + tid;
            float zf = s_z[e];
            float diff = crow[e] - zf;
            errp += diff * diff;
            float zn = zf + diff;      // zs = z + (c - z), exact straight-through fp
            s_z[e] = zn;
            z[(size_t)t0 * D2 + e] = zn;
        }
        s_red[tid] = errp;
        __syncthreads();
        for (int off = 256; off > 0; off >>= 1) {
            if (tid < off) s_red[tid] += s_red[tid + off];
            __syncthreads();
        }
        if (tid == 0) symErr[t0] += s_red[0];
        __syncthreads();
    }

    // ||zs||^2 (for con expanded distance)
    {
        float a = s_z[tid], b = s_z[512 + tid];
        s_red[tid] = a * a + b * b;
        __syncthreads();
        for (int off = 256; off > 0; off >>= 1) {
            if (tid < off) s_red[tid] += s_red[tid + off];
            __syncthreads();
        }
        if (tid == 0) s_res[2] = s_red[0];
        __syncthreads();
    }

    // con quantize: 64 codes on threads 0..63
    if (tid < 64) {
        int c = tid;
        const float4* crow = (const float4*)(con + (size_t)c * D2);
        const float4* zz = (const float4*)s_z;
        float dot = 0.f, cn2 = 0.f;
#pragma unroll 4
        for (int k4 = 0; k4 < D2 / 4; ++k4) {
            float4 cc = crow[k4], a = zz[k4];
            dot += cc.x*a.x + cc.y*a.y + cc.z*a.z + cc.w*a.w;
            cn2 += cc.x*cc.x + cc.y*cc.y + cc.z*cc.z + cc.w*cc.w;
        }
        s_red[tid] = s_res[2] + cn2 - 2.f * dot;
        s_idx[tid] = c;
    }
    __syncthreads();
    for (int off = 32; off > 0; off >>= 1) {
        if (tid < off) {
            float o = s_red[tid + off]; int oi = s_idx[tid + off];
            if (o < s_red[tid] || (o == s_red[tid] && oi < s_idx[tid])) {
                s_red[tid] = o; s_idx[tid] = oi;
            }
        }
        __syncthreads();
    }
    int ci0 = s_idx[0];
    __syncthreads();

    // conErr (direct form, vs actual zs)
    {
        const float* crow = con + (size_t)ci0 * D2;
        float p = 0.f;
#pragma unroll
        for (int r = 0; r < 2; ++r) {
            int e = r * 512 + tid;
            float diff = crow[e] - s_z[e];
            p += diff * diff;
        }
        s_red[tid] = p;
        __syncthreads();
        for (int off = 256; off > 0; off >>= 1) {
            if (tid < off) s_red[tid] += s_red[tid + off];
            __syncthreads();
        }
        if (tid == 0) conErr[t0] += s_red[0];
        __syncthreads();
    }
}

// ---------------- scatter: out[pos] = rows[x[pos]] ----------------
// grid 4096, block 256 (4 positions/block, 64 lanes x float4 each)
__global__ __launch_bounds__(256) void scatter_kernel(const int* __restrict__ x,
                                                      const float* __restrict__ rows,
                                                      float* __restrict__ out) {
    int tid = threadIdx.x;
    int pos = blockIdx.x * 4 + (tid >> 6);
    int lane = tid & 63;
    int v = x[pos];
    const float4* r = (const float4*)(rows + (size_t)v * VOCAB);
    ((float4*)(out + (size_t)pos * VOCAB))[lane] = r[lane];
}

// ---------------- losses ----------------
__global__ void loss_kernel(const int* __restrict__ hist,
                            const float* __restrict__ symErr,
                            const float* __restrict__ conErr,
                            float* __restrict__ out) {
    int tid = threadIdx.x;   // 256
    __shared__ double rs[256], rc[256];
    rs[tid] = (double)hist[tid] * (double)symErr[tid];
    rc[tid] = (double)hist[tid] * (double)conErr[tid];
    __syncthreads();
    for (int off = 128; off > 0; off >>= 1) {
        if (tid < off) { rs[tid] += rs[tid + off]; rc[tid] += rc[tid + off]; }
        __syncthreads();
    }
    if (tid == 0) {
        const double denom = (double)BS_TOT * (double)D2;   // 16777216
        out[(size_t)BS_TOT * VOCAB]     = (float)(1.25 * rs[0] / denom);
        out[(size_t)BS_TOT * VOCAB + 1] = (float)(1.25 * rc[0] / denom);
    }
}

// ---------------- host ----------------
extern "C" void kernel_launch(void* const* d_in, const int* in_sizes, int n_in,
                              void* d_out, int out_size, void* d_ws, size_t ws_size,
                              hipStream_t stream) {
    const int*   x     = (const int*)  d_in[0];
    const float* mag   = (const float*)d_in[1];
    const float* phase = (const float*)d_in[2];
    const float* Wr    = (const float*)d_in[3];
    const float* Wi    = (const float*)d_in[4];
    const float* qw    = (const float*)d_in[5];
    const float* qb    = (const float*)d_in[6];
    const float* kw    = (const float*)d_in[7];
    const float* kb    = (const float*)d_in[8];
    const float* vw    = (const float*)d_in[9];
    const float* vb    = (const float*)d_in[10];
    const float* dec_w = (const float*)d_in[11];
    const float* dec_b = (const float*)d_in[12];
    const float* sym   = (const float*)d_in[13];
    const float* con   = (const float*)d_in[14];
    float* out = (float*)d_out;

    // workspace layout (floats); total ~12.3 MB
    float* ws     = (float*)d_ws;
    float* bufA   = ws;                          // 256*1024
    float* bufB   = bufA + NTOK * D2;            // 256*1024
    float* Qbuf   = bufB + NTOK * D2;            // 256*512
    float* Kmem   = Qbuf + NTOK * DD;            // 6*256*512
    float* Vmem   = Kmem + NDEPTH * NTOK * DD;   // 6*256*1024
    float* rows   = Vmem + NDEPTH * NTOK * D2;   // 256*256
    float* snorm  = rows + NTOK * VOCAB;         // 512
    float* conf   = snorm + NSYM;                // 256
    float* symErr = conf + NTOK;                 // 256
    float* conErr = symErr + NTOK;               // 256
    int*   hist   = (int*)(conErr + NTOK);       // 256

    zero_kernel<<<1, 256, 0, stream>>>(symErr, conErr, hist);
    hist_kernel<<<BS_TOT / 256, 256, 0, stream>>>(x, hist);
    symnorm_kernel<<<NSYM, 256, 0, stream>>>(sym, snorm);
    embed_kernel<<<NTOK, 512, 0, stream>>>(mag, phase, bufA);

    float* cur = bufA;
    float* oth = bufB;
    for (int d = 0; d < NDEPTH; ++d) {
        cell_kernel<<<dim3(2, 128), 256, 0, stream>>>(cur, oth, Wr, Wi);
        { float* t = cur; cur = oth; oth = t; }
        if (d > 0) {
            matvec_kernel<2><<<dim3(2, 128), 256, 0, stream>>>(qw, qb, cur, Qbuf, D2, DD);
            attend_kernel<<<NTOK, 256, 0, stream>>>(cur, Qbuf, Kmem, Vmem, conf, d);
        }
        quantize_kernel<<<NTOK, 512, 0, stream>>>(cur, sym, snorm, con, conf, symErr, conErr);
        matvec_kernel<2><<<dim3(2, 128), 256, 0, stream>>>(kw, kb, cur,
                                                           Kmem + (size_t)d * NTOK * DD, D2, DD);
        matvec_kernel<4><<<dim3(4, 64), 256, 0, stream>>>(vw, vb, cur,
                                                          Vmem + (size_t)d * NTOK * D2, D2, D2);
    }
    for (int l = 0; l < NLOOK; ++l) {
        cell_kernel<<<dim3(2, 128), 256, 0, stream>>>(cur, oth, Wr, Wi);
        { float* t = cur; cur = oth; oth = t; }
    }
    matvec_kernel<2><<<dim3(1, 128), 256, 0, stream>>>(dec_w, dec_b, cur, rows, D2, VOCAB);
    scatter_kernel<<<BS_TOT / 4, 256, 0, stream>>>(x, rows, out);
    loss_kernel<<<1, 256, 0, stream>>>(hist, symErr, conErr, out);
}